// Round 1
// baseline (17.170 us; speedup 1.0000x reference)
//
#include <hip/hip_runtime.h>
#include <math.h>

#define GN 512
#define GB 2
#define INCH 128
#define GD 64
#define ALPHA 0.2f
#define NEG_INF_F (-9e15f)

// Kernel 1: hidden[b,n,:] = x[b,n,:] @ W  (one block per row, 64 threads = 1 wave)
// also s1[n] = a[0:64]·hidden_row, s2[n] = a[64:128]·hidden_row, s12 = s1+s2
__global__ __launch_bounds__(64) void k_hidden(
        const float* __restrict__ x, const float* __restrict__ W,
        const float* __restrict__ a,
        float* __restrict__ hidden, float* __restrict__ s1,
        float* __restrict__ s2, float* __restrict__ s12) {
    const int row = blockIdx.x;      // b*GN + n
    const int d = threadIdx.x;       // 0..63
    __shared__ float xs[INCH];
    const float* xr = x + (size_t)row * INCH;
    xs[d] = xr[d];
    xs[d + 64] = xr[d + 64];
    __syncthreads();
    float h = 0.f;
    #pragma unroll
    for (int k = 0; k < INCH; ++k) h = fmaf(xs[k], W[k * GD + d], h);
    hidden[(size_t)row * GD + d] = h;
    float p1 = a[d] * h;
    float p2 = a[GD + d] * h;
    #pragma unroll
    for (int off = 32; off > 0; off >>= 1) {
        p1 += __shfl_down(p1, off, 64);
        p2 += __shfl_down(p2, off, 64);
    }
    if (d == 0) { s1[row] = p1; s2[row] = p2; s12[row] = p1 + p2; }
}

// Kernel 2: per (b,i): masked leaky-relu logits -> softmax -> out = attn @ hidden + bias
// Closed-form logits (derived from the reference's repeat/tile/cat/reshape):
//   i < 256 : pre(j) = s12[2i + (j>=256)]
//   i >= 256: pre(j) = s1[2*(j%256)] + s2[2*(j%256)+1]
__global__ __launch_bounds__(256) void k_attn(
        const int* __restrict__ adj, const float* __restrict__ hidden,
        const float* __restrict__ s1, const float* __restrict__ s2,
        const float* __restrict__ s12, const float* __restrict__ bias,
        float* __restrict__ out) {
    const int blk = blockIdx.x;
    const int b = blk >> 9;          // / GN
    const int i = blk & (GN - 1);    // % GN
    const int tid = threadIdx.x;
    const int lane = tid & 63;
    const int wave = tid >> 6;

    __shared__ float p[GN];
    __shared__ float red[8];
    __shared__ float acc[4][GD];

    const int* adjrow = adj + ((size_t)b * GN + i) * GN;
    const float* s1b  = s1  + b * GN;
    const float* s2b  = s2  + b * GN;
    const float* s12b = s12 + b * GN;

    float v[2];
    #pragma unroll
    for (int t = 0; t < 2; ++t) {
        const int j = tid + t * 256;
        float pre;
        if (i < 256) {
            pre = s12b[2 * i + (j >= 256 ? 1 : 0)];
        } else {
            const int m = j & 255;
            pre = s1b[2 * m] + s2b[2 * m + 1];
        }
        pre = (pre >= 0.f) ? pre : ALPHA * pre;
        v[t] = (adjrow[j] > 0) ? pre : NEG_INF_F;
    }

    // block max over 512 logits
    float mx = fmaxf(v[0], v[1]);
    #pragma unroll
    for (int off = 32; off > 0; off >>= 1) mx = fmaxf(mx, __shfl_xor(mx, off, 64));
    if (lane == 0) red[wave] = mx;
    __syncthreads();
    mx = fmaxf(fmaxf(red[0], red[1]), fmaxf(red[2], red[3]));

    // exp + block sum (unnormalized weights in LDS)
    const float e0 = expf(v[0] - mx);
    const float e1 = expf(v[1] - mx);
    p[tid] = e0;
    p[tid + 256] = e1;
    float s = e0 + e1;
    #pragma unroll
    for (int off = 32; off > 0; off >>= 1) s += __shfl_xor(s, off, 64);
    if (lane == 0) red[4 + wave] = s;
    __syncthreads();
    const float inv = 1.f / (red[4] + red[5] + red[6] + red[7]);

    // out[d] = inv * sum_j p[j] * hidden[b,j,d]   (4 waves split j into 4 chunks)
    const int d = tid & 63;
    const int c = wave;
    const float* hb = hidden + (size_t)b * GN * GD;
    float av = 0.f;
    const int j0 = c * 128;
    #pragma unroll 8
    for (int j = j0; j < j0 + 128; ++j)
        av = fmaf(p[j], hb[(size_t)j * GD + d], av);
    acc[c][d] = av;
    __syncthreads();
    if (tid < GD) {
        const float o = (acc[0][tid] + acc[1][tid] + acc[2][tid] + acc[3][tid]) * inv
                        + bias[tid];
        out[((size_t)b * GN + i) * GD + tid] = o;
    }
}

extern "C" void kernel_launch(void* const* d_in, const int* in_sizes, int n_in,
                              void* d_out, int out_size, void* d_ws, size_t ws_size,
                              hipStream_t stream) {
    const float* x    = (const float*)d_in[0];
    const int*   adj  = (const int*)d_in[1];
    const float* W    = (const float*)d_in[2];
    const float* a    = (const float*)d_in[3];
    const float* bias = (const float*)d_in[4];
    float* out = (float*)d_out;

    // ws layout (floats): hidden[GB*GN*GD] | s1[GB*GN] | s2[GB*GN] | s12[GB*GN]
    float* ws     = (float*)d_ws;
    float* hidden = ws;
    float* s1     = hidden + GB * GN * GD;
    float* s2     = s1 + GB * GN;
    float* s12    = s2 + GB * GN;

    k_hidden<<<GB * GN, 64, 0, stream>>>(x, W, a, hidden, s1, s2, s12);
    k_attn<<<GB * GN, 256, 0, stream>>>(adj, hidden, s1, s2, s12, bias, out);
}

// Round 2
// 15.923 us; speedup vs baseline: 1.0783x; 1.0783x over previous
//
#include <hip/hip_runtime.h>
#include <math.h>

#define GN 512
#define GB 2
#define INCH 128
#define GD 64
#define ALPHA 0.2f
#define NEG_INF_F (-9e15f)
#define TI 4   // attention rows per k_attn block

// Kernel 1: hidden = x @ W, plus per-row scalars s1 = a[0:64]·h, s2 = a[64:128]·h.
// 256 blocks x 256 threads; each block computes 4 rows with W staged in LDS.
__global__ __launch_bounds__(256) void k_hidden(
        const float* __restrict__ x, const float* __restrict__ W,
        const float* __restrict__ a,
        float* __restrict__ hidden, float* __restrict__ s1,
        float* __restrict__ s2, float* __restrict__ s12) {
    const int row0 = blockIdx.x * 4;       // flat row b*GN+n, 0..1023
    const int tid = threadIdx.x;
    __shared__ float Wl[INCH * GD];        // 32 KB
    __shared__ float xs[4][INCH];          // 2 KB

    const float4* W4 = (const float4*)W;
    float4* Wl4 = (float4*)Wl;
    #pragma unroll
    for (int idx = tid; idx < INCH * GD / 4; idx += 256) Wl4[idx] = W4[idx];
    const float4* x4 = (const float4*)(x + (size_t)row0 * INCH);
    if (tid < 4 * INCH / 4) ((float4*)xs)[tid] = x4[tid];
    __syncthreads();

    const int r = tid >> 6, d = tid & 63;
    float h = 0.f;
    #pragma unroll
    for (int k = 0; k < INCH; ++k) h = fmaf(xs[r][k], Wl[k * GD + d], h);
    hidden[(size_t)(row0 + r) * GD + d] = h;

    float p1 = a[d] * h, p2 = a[GD + d] * h;
    #pragma unroll
    for (int off = 32; off > 0; off >>= 1) {
        p1 += __shfl_xor(p1, off, 64);
        p2 += __shfl_xor(p2, off, 64);
    }
    if (d == 0) { s1[row0 + r] = p1; s2[row0 + r] = p2; s12[row0 + r] = p1 + p2; }
}

// Kernel 2: per (b,i): masked leaky-relu logits -> softmax -> out = attn @ hidden + bias.
// Closed-form logits (from the reference's repeat/tile/cat/reshape, validated r1):
//   i < 256 : pre(j) = s12[2i + (j>=256)]
//   i >= 256: pre(j) = s1[2*(j%256)] + s2[2*(j%256)+1]
// 256 blocks x 512 threads; each block does TI=4 rows. Wave r (r<4) does row r's
// softmax; then all 8 waves split the j-range (64 each) for the PV mat-vec,
// reusing each hidden load across the 4 rows.
__global__ __launch_bounds__(512) void k_attn(
        const int* __restrict__ adj, const float* __restrict__ hidden,
        const float* __restrict__ s1, const float* __restrict__ s2,
        const float* __restrict__ s12, const float* __restrict__ bias,
        float* __restrict__ out) {
    const int blk = blockIdx.x;            // 256 blocks
    const int b = blk >> 7;
    const int i0 = (blk & 127) * TI;
    const int tid = threadIdx.x;
    const int lane = tid & 63;
    const int w = tid >> 6;                // 0..7

    __shared__ float pl[TI][GN];           // 8 KB softmax weights (unnormalized)
    __shared__ float red[8][TI][GD];       // 8 KB cross-wave partials
    __shared__ float invs[TI];

    const float* s1b  = s1  + b * GN;
    const float* s2b  = s2  + b * GN;
    const float* s12b = s12 + b * GN;

    if (w < TI) {
        const int i = i0 + w;
        const int* adjrow = adj + ((size_t)b * GN + i) * GN;
        float v[8];
        if (i < 256) {
            float c0 = s12b[2 * i], c1 = s12b[2 * i + 1];
            c0 = c0 >= 0.f ? c0 : ALPHA * c0;
            c1 = c1 >= 0.f ? c1 : ALPHA * c1;
            #pragma unroll
            for (int seg = 0; seg < 8; ++seg) {
                const int j = seg * 64 + lane;
                v[seg] = adjrow[j] > 0 ? (seg < 4 ? c0 : c1) : NEG_INF_F;
            }
        } else {
            #pragma unroll
            for (int seg = 0; seg < 8; ++seg) {
                const int j = seg * 64 + lane;
                const int m = j & 255;
                float pre = s1b[2 * m] + s2b[2 * m + 1];
                pre = pre >= 0.f ? pre : ALPHA * pre;
                v[seg] = adjrow[j] > 0 ? pre : NEG_INF_F;
            }
        }
        float mx = v[0];
        #pragma unroll
        for (int seg = 1; seg < 8; ++seg) mx = fmaxf(mx, v[seg]);
        #pragma unroll
        for (int off = 32; off > 0; off >>= 1) mx = fmaxf(mx, __shfl_xor(mx, off, 64));
        float s = 0.f;
        #pragma unroll
        for (int seg = 0; seg < 8; ++seg) {
            const float e = expf(v[seg] - mx);
            pl[w][seg * 64 + lane] = e;
            s += e;
        }
        #pragma unroll
        for (int off = 32; off > 0; off >>= 1) s += __shfl_xor(s, off, 64);
        if (lane == 0) invs[w] = 1.f / s;
    }
    __syncthreads();

    // PV: wave w handles j in [w*64, w*64+64); lane owns column d = lane.
    const float* hb = hidden + (size_t)b * GN * GD;
    const int j0 = w * 64;
    float acc0 = 0.f, acc1 = 0.f, acc2 = 0.f, acc3 = 0.f;
    #pragma unroll 4
    for (int jj = 0; jj < 64; jj += 4) {
        const int j = j0 + jj;
        const float4 q0 = *(const float4*)&pl[0][j];
        const float4 q1 = *(const float4*)&pl[1][j];
        const float4 q2 = *(const float4*)&pl[2][j];
        const float4 q3 = *(const float4*)&pl[3][j];
        float hv;
        hv = hb[(size_t)(j + 0) * GD + lane];
        acc0 = fmaf(q0.x, hv, acc0); acc1 = fmaf(q1.x, hv, acc1);
        acc2 = fmaf(q2.x, hv, acc2); acc3 = fmaf(q3.x, hv, acc3);
        hv = hb[(size_t)(j + 1) * GD + lane];
        acc0 = fmaf(q0.y, hv, acc0); acc1 = fmaf(q1.y, hv, acc1);
        acc2 = fmaf(q2.y, hv, acc2); acc3 = fmaf(q3.y, hv, acc3);
        hv = hb[(size_t)(j + 2) * GD + lane];
        acc0 = fmaf(q0.z, hv, acc0); acc1 = fmaf(q1.z, hv, acc1);
        acc2 = fmaf(q2.z, hv, acc2); acc3 = fmaf(q3.z, hv, acc3);
        hv = hb[(size_t)(j + 3) * GD + lane];
        acc0 = fmaf(q0.w, hv, acc0); acc1 = fmaf(q1.w, hv, acc1);
        acc2 = fmaf(q2.w, hv, acc2); acc3 = fmaf(q3.w, hv, acc3);
    }
    red[w][0][lane] = acc0; red[w][1][lane] = acc1;
    red[w][2][lane] = acc2; red[w][3][lane] = acc3;
    __syncthreads();

    if (tid < TI * GD) {
        const int r = tid >> 6, d = tid & 63;
        float o = 0.f;
        #pragma unroll
        for (int ww = 0; ww < 8; ++ww) o += red[ww][r][d];
        o = o * invs[r] + bias[d];
        out[((size_t)b * GN + i0 + r) * GD + d] = o;
    }
}

extern "C" void kernel_launch(void* const* d_in, const int* in_sizes, int n_in,
                              void* d_out, int out_size, void* d_ws, size_t ws_size,
                              hipStream_t stream) {
    const float* x    = (const float*)d_in[0];
    const int*   adj  = (const int*)d_in[1];
    const float* W    = (const float*)d_in[2];
    const float* a    = (const float*)d_in[3];
    const float* bias = (const float*)d_in[4];
    float* out = (float*)d_out;

    // ws layout (floats): hidden[GB*GN*GD] | s1[GB*GN] | s2[GB*GN] | s12[GB*GN]
    float* ws     = (float*)d_ws;
    float* hidden = ws;
    float* s1f    = hidden + GB * GN * GD;
    float* s2f    = s1f + GB * GN;
    float* s12f   = s2f + GB * GN;

    k_hidden<<<GB * GN / 4, 256, 0, stream>>>(x, W, a, hidden, s1f, s2f, s12f);
    k_attn<<<GB * GN / TI, 512, 0, stream>>>(adj, hidden, s1f, s2f, s12f, bias, out);
}